// Round 10
// baseline (1133.314 us; speedup 1.0000x reference)
//
#include <hip/hip_runtime.h>
#include <cstdint>
#include <cstddef>

#define N_NODES 100000
#define N_EDGES 1600000
#define F_INDIM 128
#define HDIM 256
#define C_OUT 40
#define BN_EPS 1e-5f

typedef unsigned short bf16_t;
typedef __attribute__((ext_vector_type(8))) short bf16x8;
typedef __attribute__((ext_vector_type(4))) float f32x4;

__device__ __forceinline__ float bf2f(unsigned int u) {
  return __uint_as_float(u << 16);
}
__device__ __forceinline__ bf16_t f2bf(float f) {
  unsigned int x = __float_as_uint(f);
  return (bf16_t)((x + 0x7fffu + ((x >> 16) & 1u)) >> 16);
}

// ---------------- f32 -> bf16 conversion (n % 4 == 0) ----------------
__global__ void k_cvt(const float* __restrict__ s, bf16_t* __restrict__ d, int n) {
  int i = (blockIdx.x * blockDim.x + threadIdx.x) * 4;
  if (i >= n) return;
  float4 v = *reinterpret_cast<const float4*>(&s[i]);
  uint2 o;
  o.x = (unsigned)f2bf(v.x) | ((unsigned)f2bf(v.y) << 16);
  o.y = (unsigned)f2bf(v.z) | ((unsigned)f2bf(v.w) << 16);
  *reinterpret_cast<uint2*>(&d[i]) = o;
}

// ---------------- CSR build (merged hist+rank, atomic-free placement) -------
__global__ void k_rank(const int* __restrict__ dst, int* __restrict__ cursor,
                       int* __restrict__ rank, int E) {
  for (int e = blockIdx.x * blockDim.x + threadIdx.x; e < E; e += gridDim.x * blockDim.x)
    rank[e] = atomicAdd(&cursor[dst[e]], 1);
}

__global__ __launch_bounds__(1024)
void k_scan_local(const int* __restrict__ cnt, int* __restrict__ row_ptr,
                  int* __restrict__ blk_sum, int n) {
  __shared__ int buf[1024];
  int tid = threadIdx.x;
  int i = blockIdx.x * 1024 + tid;
  int v = (i < n) ? cnt[i] : 0;
  buf[tid] = v;
  __syncthreads();
  for (int off = 1; off < 1024; off <<= 1) {
    int t = (tid >= off) ? buf[tid - off] : 0;
    __syncthreads();
    buf[tid] += t;
    __syncthreads();
  }
  if (i < n) row_ptr[i] = buf[tid] - v;       // block-local exclusive
  if (tid == 1023) blk_sum[blockIdx.x] = buf[1023];
}

__global__ __launch_bounds__(128)
void k_scan_blk(const int* __restrict__ blk_sum, int* __restrict__ blk_off, int nb) {
  __shared__ int buf[128];
  int tid = threadIdx.x;
  int v = (tid < nb) ? blk_sum[tid] : 0;
  buf[tid] = v;
  __syncthreads();
  for (int off = 1; off < 128; off <<= 1) {
    int t = (tid >= off) ? buf[tid - off] : 0;
    __syncthreads();
    buf[tid] += t;
    __syncthreads();
  }
  if (tid < nb) blk_off[tid] = buf[tid] - v;  // exclusive
}

__global__ void k_scan_add(int* __restrict__ row_ptr, const int* __restrict__ blk_off, int n) {
  int i = blockIdx.x * blockDim.x + threadIdx.x;
  if (i < n) row_ptr[i] += blk_off[i >> 10];
  if (i == 0) row_ptr[n] = N_EDGES;
}

__global__ void k_place(const int* __restrict__ src, const int* __restrict__ dst,
                        const int* __restrict__ rank, const int* __restrict__ row_ptr,
                        int* __restrict__ csr, int E) {
  for (int e = blockIdx.x * blockDim.x + threadIdx.x; e < E; e += gridDim.x * blockDim.x)
    csr[row_ptr[dst[e]] + rank[e]] = src[e];
}

__global__ void k_inv(const int* __restrict__ cnt, float* __restrict__ inv, int n) {
  int i = blockIdx.x * blockDim.x + threadIdx.x;
  if (i < n) inv[i] = 1.0f / (float)(cnt[i] > 0 ? cnt[i] : 1);
}

// ---------------- mean aggregation ----------------
__device__ __forceinline__ void add8(float* acc, uint4 r) {
  acc[0] += bf2f(r.x & 0xffffu); acc[1] += bf2f(r.x >> 16);
  acc[2] += bf2f(r.y & 0xffffu); acc[3] += bf2f(r.y >> 16);
  acc[4] += bf2f(r.z & 0xffffu); acc[5] += bf2f(r.z >> 16);
  acc[6] += bf2f(r.w & 0xffffu); acc[7] += bf2f(r.w >> 16);
}

__global__ __launch_bounds__(256)
void k_aggregate(const bf16_t* __restrict__ h, const int* __restrict__ row_ptr,
                 const int* __restrict__ csr, const float* __restrict__ inv_deg,
                 bf16_t* __restrict__ mean) {
  int w = threadIdx.x >> 6, lane = threadIdx.x & 63;
  int node = blockIdx.x * 4 + w;
  if (node >= N_NODES) return;
  int beg = row_ptr[node], end = row_ptr[node + 1];
  int half = lane >> 5;         // 0 or 1: which edge of the pair
  int l32 = lane & 31;          // 16B column block within the row
  float acc[8] = {};
  int deg = end - beg;
  int p = beg;
  int p8 = beg + (deg & ~7);
  for (; p < p8; p += 8) {       // 8 edges per iteration, 4 row loads/lane in flight
    int s0 = csr[p + half];
    int s1 = csr[p + 2 + half];
    int s2 = csr[p + 4 + half];
    int s3 = csr[p + 6 + half];
    uint4 r0 = *reinterpret_cast<const uint4*>(&h[(size_t)s0 * HDIM + l32 * 8]);
    uint4 r1 = *reinterpret_cast<const uint4*>(&h[(size_t)s1 * HDIM + l32 * 8]);
    uint4 r2 = *reinterpret_cast<const uint4*>(&h[(size_t)s2 * HDIM + l32 * 8]);
    uint4 r3 = *reinterpret_cast<const uint4*>(&h[(size_t)s3 * HDIM + l32 * 8]);
    add8(acc, r0);
    add8(acc, r1);
    add8(acc, r2);
    add8(acc, r3);
  }
  if (end - p >= 4) {            // 4-edge block: 2 row loads in flight
    int s0 = csr[p + half];
    int s1 = csr[p + 2 + half];
    uint4 r0 = *reinterpret_cast<const uint4*>(&h[(size_t)s0 * HDIM + l32 * 8]);
    uint4 r1 = *reinterpret_cast<const uint4*>(&h[(size_t)s1 * HDIM + l32 * 8]);
    add8(acc, r0);
    add8(acc, r1);
    p += 4;
  }
  for (; p < end; p += 2) {      // tail: <=3 edges, pair-guarded
    int e = p + half;
    if (e < end) {
      int s = csr[e];
      uint4 r = *reinterpret_cast<const uint4*>(&h[(size_t)s * HDIM + l32 * 8]);
      add8(acc, r);
    }
  }
#pragma unroll
  for (int k = 0; k < 8; ++k) acc[k] += __shfl_xor(acc[k], 32);
  if (half == 0) {
    float iv = inv_deg[node];
    uint4 o;
    o.x = (unsigned)f2bf(acc[0] * iv) | ((unsigned)f2bf(acc[1] * iv) << 16);
    o.y = (unsigned)f2bf(acc[2] * iv) | ((unsigned)f2bf(acc[3] * iv) << 16);
    o.z = (unsigned)f2bf(acc[4] * iv) | ((unsigned)f2bf(acc[5] * iv) << 16);
    o.w = (unsigned)f2bf(acc[6] * iv) | ((unsigned)f2bf(acc[7] * iv) << 16);
    *reinterpret_cast<uint4*>(&mean[(size_t)node * HDIM + l32 * 8]) = o;
  }
}

// ---------------- output store helpers ----------------
__device__ __forceinline__ void store1(float* p, float v) { *p = v; }
__device__ __forceinline__ void store1(bf16_t* p, float v) { *p = f2bf(v); }

// ---------------- bf16 MFMA GEMM, full-width 128x256 tile -------------------
// C[M,OUT] = act( A0 @ W0^T (+ A1 @ W1^T) + bias ), W row-major [OUT,K] bf16.
// Tile 128 rows x 256 cols (grid.y == 1): each A panel fetched ONCE.
// BK=32, 4 waves (2x2), per wave 64x128 = acc[4][8] frags of 16x16x32.
// LDS: linear A[128][32] + B[256][32], double-buffered (48 KB).
// Staging: global_load_lds 16B/lane (m97); per-lane source row = chunk*16+lane/4,
// k-off = (lane&3)*8. A: chunks wid*2+{0,1}; B: chunks wid*4+{0..3}.
template <typename TOUT>
__global__ __launch_bounds__(256)
void gemm_mfma(const bf16_t* __restrict__ A0, const bf16_t* __restrict__ W0,
               const bf16_t* __restrict__ A1, const bf16_t* __restrict__ W1,
               const float* __restrict__ bias, const float* __restrict__ bn,
               TOUT* __restrict__ C, int M, int K, int OUT, int dual) {
  __shared__ bf16_t ldsA[2][128 * 32];
  __shared__ bf16_t ldsB[2][256 * 32];
  const int tid = threadIdx.x;
  const int lane = tid & 63, wid = tid >> 6;
  const int wm = wid >> 1, wn = wid & 1;
  const int row0 = blockIdx.x * 128;
  const int l15 = lane & 15, l4 = lane >> 4;

  const int nk = K / 32;
  const int nsteps = dual ? nk * 2 : nk;

  f32x4 acc[4][8] = {};

  const int srow = lane >> 2;            // row within a 16-row chunk
  const int skk = (lane & 3) * 8;        // bf16 elem offset within BK

  auto stage = [&](int s, int b) {
    const bf16_t* A = (s < nk) ? A0 : A1;
    const bf16_t* W = (s < nk) ? W0 : W1;
    int kk0 = ((s < nk) ? s : s - nk) * 32 + skk;
#pragma unroll
    for (int c = 0; c < 2; ++c) {        // A: 8 chunks of 16 rows
      int chunk = wid * 2 + c;
      int ar = row0 + chunk * 16 + srow; if (ar >= M) ar = M - 1;
      __builtin_amdgcn_global_load_lds(
          (const __attribute__((address_space(1))) unsigned int*)&A[(size_t)ar * K + kk0],
          (__attribute__((address_space(3))) unsigned int*)&ldsA[b][chunk * 512],
          16, 0, 0);
    }
#pragma unroll
    for (int c = 0; c < 4; ++c) {        // B: 16 chunks of 16 rows
      int chunk = wid * 4 + c;
      int br = chunk * 16 + srow; if (br >= OUT) br = OUT - 1;
      __builtin_amdgcn_global_load_lds(
          (const __attribute__((address_space(1))) unsigned int*)&W[(size_t)br * K + kk0],
          (__attribute__((address_space(3))) unsigned int*)&ldsB[b][chunk * 512],
          16, 0, 0);
    }
  };

  stage(0, 0);
  __syncthreads();               // drains vmcnt(0): buffer 0 ready
  int cur = 0;
  for (int s = 0; s < nsteps; ++s) {
    if (s + 1 < nsteps) stage(s + 1, cur ^ 1);   // async into other buffer
    const bf16_t* pa = &ldsA[cur][l15 * 32 + l4 * 8];
    const bf16_t* pb = &ldsB[cur][l15 * 32 + l4 * 8];
    bf16x8 a[4], b[8];
#pragma unroll
    for (int i = 0; i < 4; ++i)
      a[i] = *reinterpret_cast<const bf16x8*>(&pa[(wm * 64 + i * 16) * 32]);
#pragma unroll
    for (int j = 0; j < 8; ++j)
      b[j] = *reinterpret_cast<const bf16x8*>(&pb[(wn * 128 + j * 16) * 32]);
#pragma unroll
    for (int i = 0; i < 4; ++i)
#pragma unroll
      for (int j = 0; j < 8; ++j)
        acc[i][j] = __builtin_amdgcn_mfma_f32_16x16x32_bf16(a[i], b[j], acc[i][j], 0, 0, 0);
    if (s + 1 < nsteps) {
      __syncthreads();           // all reads of cur done AND staged buffer drained
      cur ^= 1;
    }
  }

  // epilogue: C/D frag mapping col=lane&15, row=(lane>>4)*4+reg  [m89]
#pragma unroll
  for (int j = 0; j < 8; ++j) {
    int col = wn * 128 + j * 16 + l15;
    if (col >= OUT) continue;
    float bs = bias ? bias[col] : 0.f;
    float scale = 1.f, shift = bs;
    bool has_bn = (bn != nullptr);
    if (has_bn) {
      float g = bn[col], bb = bn[256 + col], mm = bn[512 + col], vv = bn[768 + col];
      float is = g * rsqrtf(vv + BN_EPS);
      scale = is; shift = (bs - mm) * is + bb;
    }
#pragma unroll
    for (int i = 0; i < 4; ++i) {
#pragma unroll
      for (int r = 0; r < 4; ++r) {
        int row = row0 + wm * 64 + i * 16 + l4 * 4 + r;
        if (row >= M) continue;
        float v = acc[i][j][r];
        v = has_bn ? fmaxf(v * scale + shift, 0.f) : (v + bs);
        store1(&C[(size_t)row * OUT + col], v);
      }
    }
  }
}

// ---------------- row log-softmax (C=40) ----------------
__global__ __launch_bounds__(256)
void k_logsoftmax(const float* __restrict__ logits, float* __restrict__ out, int M) {
  int row = blockIdx.x * 4 + (threadIdx.x >> 6);
  if (row >= M) return;
  int lane = threadIdx.x & 63;
  float v = (lane < C_OUT) ? logits[(size_t)row * C_OUT + lane] : -1e30f;
  float m = v;
#pragma unroll
  for (int o = 32; o; o >>= 1) m = fmaxf(m, __shfl_xor(m, o));
  float e = (lane < C_OUT) ? expf(v - m) : 0.f;
  float s = e;
#pragma unroll
  for (int o = 32; o; o >>= 1) s += __shfl_xor(s, o);
  if (lane < C_OUT) out[(size_t)row * C_OUT + lane] = v - m - logf(s);
}

// ---------------- host launch ----------------
extern "C" void kernel_launch(void* const* d_in, const int* in_sizes, int n_in,
                              void* d_out, int out_size, void* d_ws, size_t ws_size,
                              hipStream_t stream) {
  const float* x       = (const float*)d_in[0];
  const int*   ei      = (const int*)d_in[1];   // [2, E] int32
  const float* pre_w   = (const float*)d_in[2];
  const float* pre_b   = (const float*)d_in[3];
  const float* bn      = (const float*)d_in[4]; // [5,4,256]
  const float* lin_l_w = (const float*)d_in[5];
  const float* lin_l_b = (const float*)d_in[6];
  const float* lin_r_w = (const float*)d_in[7];
  const float* post1_w = (const float*)d_in[8];
  const float* post1_b = (const float*)d_in[9];
  const float* post2_w = (const float*)d_in[10];
  const float* post2_b = (const float*)d_in[11];
  float* out = (float*)d_out;

  const int* src = ei;
  const int* dstv = ei + N_EDGES;

  char* base = (char*)d_ws;
  size_t off = 0;
  auto alloc = [&](size_t bytes) -> void* {
    void* p = base + off;
    off = (off + bytes + 255) & ~(size_t)255;
    return p;
  };
  bf16_t* hA = (bf16_t*)alloc((size_t)N_NODES * HDIM * 2);
  bf16_t* hB = (bf16_t*)alloc((size_t)N_NODES * HDIM * 2);  // also x_bf16 pre-GEMM, f32 logits post
  bf16_t* hC = (bf16_t*)alloc((size_t)N_NODES * HDIM * 2);
  int* row_ptr = (int*)alloc((size_t)(N_NODES + 1) * 4);
  int* cursor  = (int*)alloc((size_t)N_NODES * 4);   // doubles as per-node degree after k_rank
  int* csr     = (int*)alloc((size_t)N_EDGES * 4);
  int* rank    = (int*)alloc((size_t)N_EDGES * 4);
  float* inv   = (float*)alloc((size_t)N_NODES * 4);
  int* blk_sum = (int*)alloc(128 * 4);
  int* blk_off = (int*)alloc(128 * 4);
  bf16_t* w_pre = (bf16_t*)alloc((size_t)HDIM * F_INDIM * 2);
  bf16_t* w_ll  = (bf16_t*)alloc((size_t)3 * HDIM * HDIM * 2);
  bf16_t* w_lr  = (bf16_t*)alloc((size_t)3 * HDIM * HDIM * 2);
  bf16_t* w_p1  = (bf16_t*)alloc((size_t)HDIM * HDIM * 2);
  bf16_t* w_p2  = (bf16_t*)alloc((size_t)C_OUT * HDIM * 2);
  (void)n_in; (void)in_sizes; (void)out_size;
  if (off > ws_size) return;  // visible failure (zeros), no fault

  bf16_t* x_bf = hB;

  // weight/input conversions
  {
    int n;
    n = N_NODES * F_INDIM;
    k_cvt<<<(n / 4 + 255) / 256, 256, 0, stream>>>(x, x_bf, n);
    n = HDIM * F_INDIM;
    k_cvt<<<(n / 4 + 255) / 256, 256, 0, stream>>>(pre_w, w_pre, n);
    n = 3 * HDIM * HDIM;
    k_cvt<<<(n / 4 + 255) / 256, 256, 0, stream>>>(lin_l_w, w_ll, n);
    k_cvt<<<(n / 4 + 255) / 256, 256, 0, stream>>>(lin_r_w, w_lr, n);
    n = HDIM * HDIM;
    k_cvt<<<(n / 4 + 255) / 256, 256, 0, stream>>>(post1_w, w_p1, n);
    n = C_OUT * HDIM;
    k_cvt<<<(n / 4 + 255) / 256, 256, 0, stream>>>(post2_w, w_p2, n);
  }

  // CSR build: one atomic pass (rank+hist), scan, atomic-free placement
  hipMemsetAsync(cursor, 0, (size_t)N_NODES * 4, stream);
  k_rank<<<2048, 256, 0, stream>>>(dstv, cursor, rank, N_EDGES);
  int nb = (N_NODES + 1023) / 1024;  // 98
  k_scan_local<<<nb, 1024, 0, stream>>>(cursor, row_ptr, blk_sum, N_NODES);
  k_scan_blk<<<1, 128, 0, stream>>>(blk_sum, blk_off, nb);
  k_scan_add<<<(N_NODES + 255) / 256, 256, 0, stream>>>(row_ptr, blk_off, N_NODES);
  k_place<<<2048, 256, 0, stream>>>(src, dstv, rank, row_ptr, csr, N_EDGES);
  k_inv<<<(N_NODES + 255) / 256, 256, 0, stream>>>(cursor, inv, N_NODES);

  dim3 gH((N_NODES + 127) / 128, 1);   // full-width 256-col tile
  // pre: h = relu(bn0(x @ pre_w^T + pre_b))
  gemm_mfma<bf16_t><<<gH, 256, 0, stream>>>(
      x_bf, w_pre, nullptr, nullptr, pre_b, bn, hA, N_NODES, F_INDIM, HDIM, 0);

  bf16_t* hcur = hA;
  bf16_t* hnext = hC;
  for (int i = 0; i < 3; ++i) {
    k_aggregate<<<N_NODES / 4, 256, 0, stream>>>(hcur, row_ptr, csr, inv, hB);
    gemm_mfma<bf16_t><<<gH, 256, 0, stream>>>(
        hB, w_ll + (size_t)i * HDIM * HDIM,
        hcur, w_lr + (size_t)i * HDIM * HDIM,
        lin_l_b + (size_t)i * HDIM,
        bn + (size_t)(i + 1) * 4 * HDIM,
        hnext, N_NODES, HDIM, HDIM, 1);
    bf16_t* t = hcur; hcur = hnext; hnext = t;
  }
  // post1
  gemm_mfma<bf16_t><<<gH, 256, 0, stream>>>(
      hcur, w_p1, nullptr, nullptr, post1_b,
      bn + (size_t)4 * 4 * HDIM, hnext, N_NODES, HDIM, HDIM, 0);
  // post2 -> f32 logits (no bn); hB is free now
  float* logits = (float*)hB;
  gemm_mfma<float><<<gH, 256, 0, stream>>>(
      hnext, w_p2, nullptr, nullptr, post2_b,
      nullptr, logits, N_NODES, HDIM, C_OUT, 0);
  k_logsoftmax<<<(N_NODES + 3) / 4, 256, 0, stream>>>(logits, out, N_NODES);
}

// Round 11
// 783.009 us; speedup vs baseline: 1.4474x; 1.4474x over previous
//
#include <hip/hip_runtime.h>
#include <cstdint>
#include <cstddef>

#define N_NODES 100000
#define N_EDGES 1600000
#define F_INDIM 128
#define HDIM 256
#define C_OUT 40
#define BN_EPS 1e-5f

typedef unsigned short bf16_t;
typedef __attribute__((ext_vector_type(8))) short bf16x8;
typedef __attribute__((ext_vector_type(4))) float f32x4;

__device__ __forceinline__ float bf2f(unsigned int u) {
  return __uint_as_float(u << 16);
}
__device__ __forceinline__ bf16_t f2bf(float f) {
  unsigned int x = __float_as_uint(f);
  return (bf16_t)((x + 0x7fffu + ((x >> 16) & 1u)) >> 16);
}

// ---------------- f32 -> bf16 conversion (n % 4 == 0) ----------------
__global__ void k_cvt(const float* __restrict__ s, bf16_t* __restrict__ d, int n) {
  int i = (blockIdx.x * blockDim.x + threadIdx.x) * 4;
  if (i >= n) return;
  float4 v = *reinterpret_cast<const float4*>(&s[i]);
  uint2 o;
  o.x = (unsigned)f2bf(v.x) | ((unsigned)f2bf(v.y) << 16);
  o.y = (unsigned)f2bf(v.z) | ((unsigned)f2bf(v.w) << 16);
  *reinterpret_cast<uint2*>(&d[i]) = o;
}

// ---------------- CSR build (merged hist+rank, atomic-free placement) -------
__global__ void k_rank(const int* __restrict__ dst, int* __restrict__ cursor,
                       int* __restrict__ rank, int E) {
  for (int e = blockIdx.x * blockDim.x + threadIdx.x; e < E; e += gridDim.x * blockDim.x)
    rank[e] = atomicAdd(&cursor[dst[e]], 1);
}

__global__ __launch_bounds__(1024)
void k_scan_local(const int* __restrict__ cnt, int* __restrict__ row_ptr,
                  int* __restrict__ blk_sum, int n) {
  __shared__ int buf[1024];
  int tid = threadIdx.x;
  int i = blockIdx.x * 1024 + tid;
  int v = (i < n) ? cnt[i] : 0;
  buf[tid] = v;
  __syncthreads();
  for (int off = 1; off < 1024; off <<= 1) {
    int t = (tid >= off) ? buf[tid - off] : 0;
    __syncthreads();
    buf[tid] += t;
    __syncthreads();
  }
  if (i < n) row_ptr[i] = buf[tid] - v;       // block-local exclusive
  if (tid == 1023) blk_sum[blockIdx.x] = buf[1023];
}

__global__ __launch_bounds__(128)
void k_scan_blk(const int* __restrict__ blk_sum, int* __restrict__ blk_off, int nb) {
  __shared__ int buf[128];
  int tid = threadIdx.x;
  int v = (tid < nb) ? blk_sum[tid] : 0;
  buf[tid] = v;
  __syncthreads();
  for (int off = 1; off < 128; off <<= 1) {
    int t = (tid >= off) ? buf[tid - off] : 0;
    __syncthreads();
    buf[tid] += t;
    __syncthreads();
  }
  if (tid < nb) blk_off[tid] = buf[tid] - v;  // exclusive
}

__global__ void k_scan_add(int* __restrict__ row_ptr, const int* __restrict__ blk_off, int n) {
  int i = blockIdx.x * blockDim.x + threadIdx.x;
  if (i < n) row_ptr[i] += blk_off[i >> 10];
  if (i == 0) row_ptr[n] = N_EDGES;
}

__global__ void k_place(const int* __restrict__ src, const int* __restrict__ dst,
                        const int* __restrict__ rank, const int* __restrict__ row_ptr,
                        int* __restrict__ csr, int E) {
  for (int e = blockIdx.x * blockDim.x + threadIdx.x; e < E; e += gridDim.x * blockDim.x)
    csr[row_ptr[dst[e]] + rank[e]] = src[e];
}

__global__ void k_inv(const int* __restrict__ cnt, float* __restrict__ inv, int n) {
  int i = blockIdx.x * blockDim.x + threadIdx.x;
  if (i < n) inv[i] = 1.0f / (float)(cnt[i] > 0 ? cnt[i] : 1);
}

// ---------------- mean aggregation ----------------
__device__ __forceinline__ void add8(float* acc, uint4 r) {
  acc[0] += bf2f(r.x & 0xffffu); acc[1] += bf2f(r.x >> 16);
  acc[2] += bf2f(r.y & 0xffffu); acc[3] += bf2f(r.y >> 16);
  acc[4] += bf2f(r.z & 0xffffu); acc[5] += bf2f(r.z >> 16);
  acc[6] += bf2f(r.w & 0xffffu); acc[7] += bf2f(r.w >> 16);
}

__global__ __launch_bounds__(256)
void k_aggregate(const bf16_t* __restrict__ h, const int* __restrict__ row_ptr,
                 const int* __restrict__ csr, const float* __restrict__ inv_deg,
                 bf16_t* __restrict__ mean) {
  int w = threadIdx.x >> 6, lane = threadIdx.x & 63;
  int node = blockIdx.x * 4 + w;
  if (node >= N_NODES) return;
  int beg = row_ptr[node], end = row_ptr[node + 1];
  int half = lane >> 5;         // 0 or 1: which edge of the pair
  int l32 = lane & 31;          // 16B column block within the row
  float acc[8] = {};
  int deg = end - beg;
  int p = beg;
  int p8 = beg + (deg & ~7);
  for (; p < p8; p += 8) {       // 8 edges per iteration, 4 row loads/lane in flight
    int s0 = csr[p + half];
    int s1 = csr[p + 2 + half];
    int s2 = csr[p + 4 + half];
    int s3 = csr[p + 6 + half];
    uint4 r0 = *reinterpret_cast<const uint4*>(&h[(size_t)s0 * HDIM + l32 * 8]);
    uint4 r1 = *reinterpret_cast<const uint4*>(&h[(size_t)s1 * HDIM + l32 * 8]);
    uint4 r2 = *reinterpret_cast<const uint4*>(&h[(size_t)s2 * HDIM + l32 * 8]);
    uint4 r3 = *reinterpret_cast<const uint4*>(&h[(size_t)s3 * HDIM + l32 * 8]);
    add8(acc, r0);
    add8(acc, r1);
    add8(acc, r2);
    add8(acc, r3);
  }
  if (end - p >= 4) {            // 4-edge block: 2 row loads in flight
    int s0 = csr[p + half];
    int s1 = csr[p + 2 + half];
    uint4 r0 = *reinterpret_cast<const uint4*>(&h[(size_t)s0 * HDIM + l32 * 8]);
    uint4 r1 = *reinterpret_cast<const uint4*>(&h[(size_t)s1 * HDIM + l32 * 8]);
    add8(acc, r0);
    add8(acc, r1);
    p += 4;
  }
  for (; p < end; p += 2) {      // tail: <=3 edges, pair-guarded
    int e = p + half;
    if (e < end) {
      int s = csr[e];
      uint4 r = *reinterpret_cast<const uint4*>(&h[(size_t)s * HDIM + l32 * 8]);
      add8(acc, r);
    }
  }
#pragma unroll
  for (int k = 0; k < 8; ++k) acc[k] += __shfl_xor(acc[k], 32);
  if (half == 0) {
    float iv = inv_deg[node];
    uint4 o;
    o.x = (unsigned)f2bf(acc[0] * iv) | ((unsigned)f2bf(acc[1] * iv) << 16);
    o.y = (unsigned)f2bf(acc[2] * iv) | ((unsigned)f2bf(acc[3] * iv) << 16);
    o.z = (unsigned)f2bf(acc[4] * iv) | ((unsigned)f2bf(acc[5] * iv) << 16);
    o.w = (unsigned)f2bf(acc[6] * iv) | ((unsigned)f2bf(acc[7] * iv) << 16);
    *reinterpret_cast<uint4*>(&mean[(size_t)node * HDIM + l32 * 8]) = o;
  }
}

// ---------------- output store helpers ----------------
__device__ __forceinline__ void store1(float* p, float v) { *p = v; }
__device__ __forceinline__ void store1(bf16_t* p, float v) { *p = f2bf(v); }

// ---------------- bf16 MFMA GEMM, gload_lds + XOR slot-swizzle --------------
// C[M,OUT] = act( A0 @ W0^T (+ A1 @ W1^T) + bias ), W row-major [OUT,K] bf16.
// 128x128 tile, BK=32, 4 waves (2x2), 4x4 frags of 16x16x32 per wave.
// LDS: linear [128][32] A/B tiles, double-buffered (32 KB).
// Swizzle (rule #21 both-sides): physical 16B slot p at row r holds logical
// slot p ^ ((r>>1)&3). Staging keeps linear LDS dest (gload_lds requirement)
// and permutes the per-lane GLOBAL k-slot; fragment ds_read applies the same
// XOR -> quarter-wave covers all 8 bank-groups (2 lanes each, free per m136).
template <typename TOUT>
__global__ __launch_bounds__(256)
void gemm_mfma(const bf16_t* __restrict__ A0, const bf16_t* __restrict__ W0,
               const bf16_t* __restrict__ A1, const bf16_t* __restrict__ W1,
               const float* __restrict__ bias, const float* __restrict__ bn,
               TOUT* __restrict__ C, int M, int K, int OUT, int dual) {
  __shared__ bf16_t lds[2][2][128 * 32];   // [buf][A/B][row*32+k]
  const int tid = threadIdx.x;
  const int lane = tid & 63, wid = tid >> 6;
  const int wm = wid >> 1, wn = wid & 1;
  const int row0 = blockIdx.x * 128, col0 = blockIdx.y * 128;
  const int l15 = lane & 15, l4 = lane >> 4;

  const int nk = K / 32;
  const int nsteps = dual ? nk * 2 : nk;

  f32x4 acc[4][4] = {};

  // staging: lane's LDS dest (linear) is row = chunk*16 + lane/4, slot = lane&3;
  // global source uses the swizzled logical slot for that (row, slot).
  const int srow_base = wid * 32 + (lane >> 2);
  const int skk = ((lane & 3) ^ ((lane >> 3) & 3)) * 8;   // swizzled source k-slot

  auto stage = [&](int s, int b) {
    const bf16_t* A = (s < nk) ? A0 : A1;
    const bf16_t* W = (s < nk) ? W0 : W1;
    int kk0 = ((s < nk) ? s : s - nk) * 32 + skk;
#pragma unroll
    for (int c = 0; c < 2; ++c) {
      int chunk = wid * 2 + c;            // 0..7
      int row = srow_base + c * 16;       // chunk*16 + lane/4
      int ar = row0 + row; if (ar >= M) ar = M - 1;
      int br = col0 + row; if (br >= OUT) br = OUT - 1;
      __builtin_amdgcn_global_load_lds(
          (const __attribute__((address_space(1))) unsigned int*)&A[(size_t)ar * K + kk0],
          (__attribute__((address_space(3))) unsigned int*)&lds[b][0][chunk * 512],
          16, 0, 0);
      __builtin_amdgcn_global_load_lds(
          (const __attribute__((address_space(1))) unsigned int*)&W[(size_t)br * K + kk0],
          (__attribute__((address_space(3))) unsigned int*)&lds[b][1][chunk * 512],
          16, 0, 0);
    }
  };

  // fragment read: physical slot for logical slot l4 at row (…+l15)
  const int rslot = (l4 ^ ((l15 >> 1) & 3)) * 8;

  stage(0, 0);
  __syncthreads();               // drains vmcnt(0): buffer 0 ready
  int cur = 0;
  for (int s = 0; s < nsteps; ++s) {
    if (s + 1 < nsteps) stage(s + 1, cur ^ 1);   // async into other buffer
    const bf16_t* pa = &lds[cur][0][l15 * 32 + rslot];
    const bf16_t* pb = &lds[cur][1][l15 * 32 + rslot];
    bf16x8 a[4], b[4];
#pragma unroll
    for (int i = 0; i < 4; ++i)
      a[i] = *reinterpret_cast<const bf16x8*>(&pa[(wm * 64 + i * 16) * 32]);
#pragma unroll
    for (int j = 0; j < 4; ++j)
      b[j] = *reinterpret_cast<const bf16x8*>(&pb[(wn * 64 + j * 16) * 32]);
#pragma unroll
    for (int i = 0; i < 4; ++i)
#pragma unroll
      for (int j = 0; j < 4; ++j)
        acc[i][j] = __builtin_amdgcn_mfma_f32_16x16x32_bf16(a[i], b[j], acc[i][j], 0, 0, 0);
    if (s + 1 < nsteps) {
      __syncthreads();           // all reads of cur done AND staged buffer drained
      cur ^= 1;
    }
  }

  // epilogue: C/D frag mapping col=lane&15, row=(lane>>4)*4+reg  [m89]
#pragma unroll
  for (int j = 0; j < 4; ++j) {
    int col = col0 + wn * 64 + j * 16 + l15;
    if (col >= OUT) continue;
    float bs = bias ? bias[col] : 0.f;
    float scale = 1.f, shift = bs;
    bool has_bn = (bn != nullptr);
    if (has_bn) {
      float g = bn[col], bb = bn[256 + col], mm = bn[512 + col], vv = bn[768 + col];
      float is = g * rsqrtf(vv + BN_EPS);
      scale = is; shift = (bs - mm) * is + bb;
    }
#pragma unroll
    for (int i = 0; i < 4; ++i) {
#pragma unroll
      for (int r = 0; r < 4; ++r) {
        int row = row0 + wm * 64 + i * 16 + l4 * 4 + r;
        if (row >= M) continue;
        float v = acc[i][j][r];
        v = has_bn ? fmaxf(v * scale + shift, 0.f) : (v + bs);
        store1(&C[(size_t)row * OUT + col], v);
      }
    }
  }
}

// ---------------- row log-softmax (C=40) ----------------
__global__ __launch_bounds__(256)
void k_logsoftmax(const float* __restrict__ logits, float* __restrict__ out, int M) {
  int row = blockIdx.x * 4 + (threadIdx.x >> 6);
  if (row >= M) return;
  int lane = threadIdx.x & 63;
  float v = (lane < C_OUT) ? logits[(size_t)row * C_OUT + lane] : -1e30f;
  float m = v;
#pragma unroll
  for (int o = 32; o; o >>= 1) m = fmaxf(m, __shfl_xor(m, o));
  float e = (lane < C_OUT) ? expf(v - m) : 0.f;
  float s = e;
#pragma unroll
  for (int o = 32; o; o >>= 1) s += __shfl_xor(s, o);
  if (lane < C_OUT) out[(size_t)row * C_OUT + lane] = v - m - logf(s);
}

// ---------------- host launch ----------------
extern "C" void kernel_launch(void* const* d_in, const int* in_sizes, int n_in,
                              void* d_out, int out_size, void* d_ws, size_t ws_size,
                              hipStream_t stream) {
  const float* x       = (const float*)d_in[0];
  const int*   ei      = (const int*)d_in[1];   // [2, E] int32
  const float* pre_w   = (const float*)d_in[2];
  const float* pre_b   = (const float*)d_in[3];
  const float* bn      = (const float*)d_in[4]; // [5,4,256]
  const float* lin_l_w = (const float*)d_in[5];
  const float* lin_l_b = (const float*)d_in[6];
  const float* lin_r_w = (const float*)d_in[7];
  const float* post1_w = (const float*)d_in[8];
  const float* post1_b = (const float*)d_in[9];
  const float* post2_w = (const float*)d_in[10];
  const float* post2_b = (const float*)d_in[11];
  float* out = (float*)d_out;

  const int* src = ei;
  const int* dstv = ei + N_EDGES;

  char* base = (char*)d_ws;
  size_t off = 0;
  auto alloc = [&](size_t bytes) -> void* {
    void* p = base + off;
    off = (off + bytes + 255) & ~(size_t)255;
    return p;
  };
  bf16_t* hA = (bf16_t*)alloc((size_t)N_NODES * HDIM * 2);
  bf16_t* hB = (bf16_t*)alloc((size_t)N_NODES * HDIM * 2);  // also x_bf16 pre-GEMM, f32 logits post
  bf16_t* hC = (bf16_t*)alloc((size_t)N_NODES * HDIM * 2);
  int* row_ptr = (int*)alloc((size_t)(N_NODES + 1) * 4);
  int* cursor  = (int*)alloc((size_t)N_NODES * 4);   // doubles as per-node degree after k_rank
  int* csr     = (int*)alloc((size_t)N_EDGES * 4);
  int* rank    = (int*)alloc((size_t)N_EDGES * 4);
  float* inv   = (float*)alloc((size_t)N_NODES * 4);
  int* blk_sum = (int*)alloc(128 * 4);
  int* blk_off = (int*)alloc(128 * 4);
  bf16_t* w_pre = (bf16_t*)alloc((size_t)HDIM * F_INDIM * 2);
  bf16_t* w_ll  = (bf16_t*)alloc((size_t)3 * HDIM * HDIM * 2);
  bf16_t* w_lr  = (bf16_t*)alloc((size_t)3 * HDIM * HDIM * 2);
  bf16_t* w_p1  = (bf16_t*)alloc((size_t)HDIM * HDIM * 2);
  bf16_t* w_p2  = (bf16_t*)alloc((size_t)C_OUT * HDIM * 2);
  (void)n_in; (void)in_sizes; (void)out_size;
  if (off > ws_size) return;  // visible failure (zeros), no fault

  bf16_t* x_bf = hB;

  // weight/input conversions
  {
    int n;
    n = N_NODES * F_INDIM;
    k_cvt<<<(n / 4 + 255) / 256, 256, 0, stream>>>(x, x_bf, n);
    n = HDIM * F_INDIM;
    k_cvt<<<(n / 4 + 255) / 256, 256, 0, stream>>>(pre_w, w_pre, n);
    n = 3 * HDIM * HDIM;
    k_cvt<<<(n / 4 + 255) / 256, 256, 0, stream>>>(lin_l_w, w_ll, n);
    k_cvt<<<(n / 4 + 255) / 256, 256, 0, stream>>>(lin_r_w, w_lr, n);
    n = HDIM * HDIM;
    k_cvt<<<(n / 4 + 255) / 256, 256, 0, stream>>>(post1_w, w_p1, n);
    n = C_OUT * HDIM;
    k_cvt<<<(n / 4 + 255) / 256, 256, 0, stream>>>(post2_w, w_p2, n);
  }

  // CSR build: one atomic pass (rank+hist), scan, atomic-free placement
  hipMemsetAsync(cursor, 0, (size_t)N_NODES * 4, stream);
  k_rank<<<2048, 256, 0, stream>>>(dstv, cursor, rank, N_EDGES);
  int nb = (N_NODES + 1023) / 1024;  // 98
  k_scan_local<<<nb, 1024, 0, stream>>>(cursor, row_ptr, blk_sum, N_NODES);
  k_scan_blk<<<1, 128, 0, stream>>>(blk_sum, blk_off, nb);
  k_scan_add<<<(N_NODES + 255) / 256, 256, 0, stream>>>(row_ptr, blk_off, N_NODES);
  k_place<<<2048, 256, 0, stream>>>(src, dstv, rank, row_ptr, csr, N_EDGES);
  k_inv<<<(N_NODES + 255) / 256, 256, 0, stream>>>(cursor, inv, N_NODES);

  dim3 gH((N_NODES + 127) / 128, 2);   // OUT=256
  // pre: h = relu(bn0(x @ pre_w^T + pre_b))
  gemm_mfma<bf16_t><<<gH, 256, 0, stream>>>(
      x_bf, w_pre, nullptr, nullptr, pre_b, bn, hA, N_NODES, F_INDIM, HDIM, 0);

  bf16_t* hcur = hA;
  bf16_t* hnext = hC;
  for (int i = 0; i < 3; ++i) {
    k_aggregate<<<N_NODES / 4, 256, 0, stream>>>(hcur, row_ptr, csr, inv, hB);
    gemm_mfma<bf16_t><<<gH, 256, 0, stream>>>(
        hB, w_ll + (size_t)i * HDIM * HDIM,
        hcur, w_lr + (size_t)i * HDIM * HDIM,
        lin_l_b + (size_t)i * HDIM,
        bn + (size_t)(i + 1) * 4 * HDIM,
        hnext, N_NODES, HDIM, HDIM, 1);
    bf16_t* t = hcur; hcur = hnext; hnext = t;
  }
  // post1
  gemm_mfma<bf16_t><<<gH, 256, 0, stream>>>(
      hcur, w_p1, nullptr, nullptr, post1_b,
      bn + (size_t)4 * 4 * HDIM, hnext, N_NODES, HDIM, HDIM, 0);
  // post2 -> f32 logits (no bn); hB is free now
  float* logits = (float*)hB;
  dim3 gC((N_NODES + 127) / 128, 1);
  gemm_mfma<float><<<gC, 256, 0, stream>>>(
      hnext, w_p2, nullptr, nullptr, post2_b,
      nullptr, logits, N_NODES, HDIM, C_OUT, 0);
  k_logsoftmax<<<(N_NODES + 3) / 4, 256, 0, stream>>>(logits, out, N_NODES);
}